// Round 1
// 309.691 us; speedup vs baseline: 1.2174x; 1.2174x over previous
//
#include <hip/hip_runtime.h>

// ---------------------------------------------------------------------------
// IntegerCifar10Net: 4-bit quantized CNN, B=512.
// Post-layer-1 math is EXACT integer arithmetic (acts 0..7, weights -7..7,
// partial sums < 2^31) -> run it on i8 MFMA (mfma_i32_16x16x64_i8, exact i32
// accumulate, K=64 = 2x bf16 rate, raw u8/i8 staging with no cvt).
// Layer 1 stays fp64 (continuous input; must match reference quant decisions).
//
// Round-4 changes:
//  * Division-free epilogues everywhere:
//      clip(acc/S * g + b, -1, 1)*7  ==  clip(acc*(7g/S) + 7b, -7, 7)
//    and rint(clip(t,-7,7)) + relu == integer clamp of rint(t) to [0,7].
//    Removes 16 (conv1) / 64 (i8 convs) / 4 (fc1) fp64 divides per thread
//    (~40+ cyc each). Deviation is ~1 ulp fp64, far below quant margins.
//  * conv1 output now staged through LDS and written as one coalesced
//    uint4 per thread (16B chunks, px-major) instead of 16 scattered byte
//    stores -> 16x fewer store requests (was ~1024/wave -> ~64/wave).
//  * All 8 weight-prep launches fused into one segment-dispatched kernel.
// Inter-layer activations: NHWC u8 (value = 7 * real activation).
// LDS conv layout: 4 k-chunk planes (chunk q at q*PLANE + row*16) to break
// the 64B-row-stride bank aliasing.
// ---------------------------------------------------------------------------

typedef __attribute__((ext_vector_type(4))) int v4i;

// workspace offsets (bytes)
#define O_QW1    0u          // 1728    i8 conv1 [64][3][9]
#define O_QWF2   4096u       // 5120    i8 fc2   [10][512]
#define O_QWT2   16384u      // 36864   i8 [64][9][64]
#define O_QWT3   65536u      // 73728   i8 [128][9][64]
#define O_QWT4   147456u     // 147456  i8 [128][9][128]
#define O_QWT5   294912u     // 294912  i8 [256][9][128]
#define O_QWT6   589824u     // 589824  i8 [256][9][256]
#define O_QWF1   1179648u    // 2097152 i8 [512][4096] k reordered to NHWC
#define O_BUFA   3276800u    // 33.5 MB
#define O_BUFB   36831232u   // 8.4 MB  (total ~45.2 MB)

// ---------------------------------------------------------------------------
// fused weight prep: one launch, segment-dispatched by blockIdx.x
// ---------------------------------------------------------------------------
__device__ __forceinline__ signed char quant_w(double v) {
    return (signed char)(int)rint(fmin(fmax(v, -1.0), 1.0) * 7.0);
}

__device__ __forceinline__ void quantw_body(const float* __restrict__ w,
                                            signed char* __restrict__ q, int i, int n) {
    if (i < n) q[i] = quant_w((double)w[i]);
}

// conv weights: fp32 [CO][CI][3][3] -> i8 [CO][9][CI]
__device__ __forceinline__ void quantw_t8_body(const float* __restrict__ w,
                                               signed char* __restrict__ o,
                                               int CI, int i, int n) {
    if (i < n) {
        int co  = i / (9 * CI);
        int rem = i - co * 9 * CI;
        int t   = rem / CI;
        int ci  = rem - t * CI;
        o[i] = quant_w((double)w[(co * CI + ci) * 9 + t]);
    }
}

// fc1 weights: fp32 [512][4096 nchw-k] -> i8 [512][4096 nhwc-k]
__device__ __forceinline__ void quantw_fc1_body(const float* __restrict__ w,
                                                signed char* __restrict__ o, int i) {
    if (i < 512 * 4096) {
        int j  = i >> 12;
        int kn = i & 4095;
        int px = kn >> 8;          // y*4+x
        int c  = kn & 255;
        int ko = c * 16 + px;      // nchw flat index
        o[i] = quant_w((double)w[j * 4096 + ko]);
    }
}

// block ranges: [0,7) qw1 | [7,27) qwf2 | [27,171) qwt2 | [171,459) qwt3 |
// [459,1035) qwt4 | [1035,2187) qwt5 | [2187,4491) qwt6 | [4491,12683) qwf1
__global__ __launch_bounds__(256) void prep_k(
    const float* __restrict__ w1,  signed char* __restrict__ qw1,
    const float* __restrict__ wf2, signed char* __restrict__ qwf2,
    const float* __restrict__ w2,  signed char* __restrict__ qwt2,
    const float* __restrict__ w3,  signed char* __restrict__ qwt3,
    const float* __restrict__ w4,  signed char* __restrict__ qwt4,
    const float* __restrict__ w5,  signed char* __restrict__ qwt5,
    const float* __restrict__ w6,  signed char* __restrict__ qwt6,
    const float* __restrict__ wf1, signed char* __restrict__ qwf1)
{
    const int blk = blockIdx.x;
    const int t   = threadIdx.x;
    if      (blk < 7)    quantw_body(w1, qw1, blk * 256 + t, 1728);
    else if (blk < 27)   quantw_body(wf2, qwf2, (blk - 7) * 256 + t, 5120);
    else if (blk < 171)  quantw_t8_body(w2, qwt2, 64,  (blk - 27)   * 256 + t, 36864);
    else if (blk < 459)  quantw_t8_body(w3, qwt3, 64,  (blk - 171)  * 256 + t, 73728);
    else if (blk < 1035) quantw_t8_body(w4, qwt4, 128, (blk - 459)  * 256 + t, 147456);
    else if (blk < 2187) quantw_t8_body(w5, qwt5, 128, (blk - 1035) * 256 + t, 294912);
    else if (blk < 4491) quantw_t8_body(w6, qwt6, 256, (blk - 2187) * 256 + t, 589824);
    else                 quantw_fc1_body(wf1, qwf1, (blk - 4491) * 256 + t);
}

// ---------------------------------------------------------------------------
// conv1: 3->64, 32x32, fp64-exact, NHWC u8 output.
// Block: image b x 8-row slab x 16 co. x tile + weights staged in LDS as
// doubles (cvt once, zero-padded halo -> branch-free inner loop).
// Epilogue: division-free fp64 affine+rint, u8 results packed through LDS
// and written as one coalesced uint4 per thread.
// ---------------------------------------------------------------------------
__global__ __launch_bounds__(256) void conv1_k(
    const float* __restrict__ x, const signed char* __restrict__ wq,
    const float* __restrict__ gvec, const float* __restrict__ bvec,
    unsigned char* __restrict__ out)
{
    __shared__ double xs[3 * 10 * 34];   // [ci][10 rows][34 cols], halo included
    __shared__ double wd[16 * 27];       // [lco][ci][tap]
    __shared__ __align__(16) unsigned char ob[256 * 16];  // [px][lco] u8 out tile

    const int tid  = threadIdx.x;
    const int sp   = tid & 63;
    const int cg   = tid >> 6;
    const int img  = blockIdx.x >> 2;
    const int slab = blockIdx.x & 3;
    const int y0s  = slab * 8;
    const int co_base = blockIdx.y * 16;
    const int yb = sp >> 4, xb = sp & 15;
    const int ysl = yb * 2, x0 = xb * 2;

    for (int i = tid; i < 432; i += 256)
        wd[i] = (double)wq[co_base * 27 + i];
    for (int i = tid; i < 1020; i += 256) {
        int ci = i / 340, r = i - ci * 340;
        int ry = r / 34, rx = r - ry * 34;
        int gy = y0s - 1 + ry, gx = rx - 1;
        double v = 0.0;
        if ((unsigned)gy < 32u && (unsigned)gx < 32u)
            v = (double)x[(img * 3 + ci) * 1024 + gy * 32 + gx];
        xs[i] = v;
    }
    __syncthreads();

    double acc[4][4];
#pragma unroll
    for (int l = 0; l < 4; ++l)
#pragma unroll
        for (int p = 0; p < 4; ++p) acc[l][p] = 0.0;

#pragma unroll
    for (int ci = 0; ci < 3; ++ci) {
        double a[4][4];
#pragma unroll
        for (int iy = 0; iy < 4; ++iy)
#pragma unroll
            for (int ix = 0; ix < 4; ++ix)
                a[iy][ix] = xs[ci * 340 + (ysl + iy) * 34 + (x0 + ix)];
#pragma unroll
        for (int l = 0; l < 4; ++l) {
            const double* wr = &wd[((cg * 4 + l) * 3 + ci) * 9];
#pragma unroll
            for (int ky = 0; ky < 3; ++ky)
#pragma unroll
                for (int kx = 0; kx < 3; ++kx) {
                    const double wv = wr[ky * 3 + kx];
                    acc[l][0] = fma(wv, a[ky    ][kx    ], acc[l][0]);
                    acc[l][1] = fma(wv, a[ky    ][kx + 1], acc[l][1]);
                    acc[l][2] = fma(wv, a[ky + 1][kx    ], acc[l][2]);
                    acc[l][3] = fma(wv, a[ky + 1][kx + 1], acc[l][3]);
                }
        }
    }

    // epilogue: 7*y = acc*g + 7*b (conv=acc/7, then *7 at quant cancels);
    // q = clamp(rint(7y), 0, 7)  (relu + clip folded into the int clamp)
    int qv[4][4];
#pragma unroll
    for (int l = 0; l < 4; ++l) {
        const int co = co_base + cg * 4 + l;
        const double gg  = (double)gvec[co];
        const double bb7 = (double)bvec[co] * 7.0;
#pragma unroll
        for (int p = 0; p < 4; ++p) {
            int qi = (int)rint(fma(acc[l][p], gg, bb7));
            qv[l][p] = qi < 0 ? 0 : (qi > 7 ? 7 : qi);
        }
    }
#pragma unroll
    for (int p = 0; p < 4; ++p) {
        unsigned int wv = (unsigned int)qv[0][p]
                        | ((unsigned int)qv[1][p] << 8)
                        | ((unsigned int)qv[2][p] << 16)
                        | ((unsigned int)qv[3][p] << 24);
        const int r = ysl + (p >> 1), c = x0 + (p & 1);
        *(unsigned int*)&ob[(r * 32 + c) * 16 + cg * 4] = wv;
    }
    __syncthreads();
    {
        const int row = tid >> 5, col = tid & 31;
        uint4 v = *(const uint4*)&ob[tid * 16];
        *(uint4*)&out[((img * 32 + y0s + row) * 32 + col) * 64 + co_base] = v;
    }
}

// ---------------------------------------------------------------------------
// i8 MFMA implicit-GEMM conv: NHWC u8 in, i8 [CO][9][CI] weights, NHWC u8 out.
// Block: 256 thr = 4 waves; 64 co x 256 px. K processed in ci-chunks of 64.
// LDS: 4 planes (one per 16B k-chunk q); row r's chunk q lives at
// q*PLANE + r*16 -> quarter-wave b128 reads spread over bank-groups.
// Morton px->m mapping makes each lane's 4 acc regs a 2x2 pool window.
// Epilogue: division-free fp64 affine (7y = acc*(g/7) + 7b), int clamp.
// ---------------------------------------------------------------------------
template<int CI, int CO, int H, int W, bool POOL, int IPB>
__global__ __launch_bounds__(256, 2) void conv_i8_k(
    const unsigned char* __restrict__ in, const signed char* __restrict__ wt,
    const float* __restrict__ gvec, const float* __restrict__ bvec,
    unsigned char* __restrict__ out)
{
    constexpr int ATX    = (IPB == 1) ? 18 : 10;
    constexpr int APX    = ATX * ATX;
    constexpr int APLANE = IPB * APX * 16;       // bytes per act plane
    constexpr int WBASE  = 4 * APLANE;
    constexpr int WPLANE = 576 * 16;             // 64 co x 9 taps rows
    constexpr int NPASS  = CI / 64;

    __shared__ __align__(16) char lds[WBASE + 4 * WPLANE];

    const int tid = threadIdx.x;
    const int l   = tid & 63;
    const int w   = tid >> 6;
    const int n   = l & 15;
    const int q   = l >> 4;

    int img = 0, regY0 = 0, regX0 = 0, wy8 = 0, wx8 = 0, tilepx = 0;
    if (IPB == 1) {
        constexpr int rpw = W / 16;
        constexpr int rpi = (H / 16) * rpw;
        img   = blockIdx.x / rpi;
        int r = blockIdx.x % rpi;
        regY0 = (r / rpw) * 16;
        regX0 = (r % rpw) * 16;
        wy8 = (w >> 1) * 8; wx8 = (w & 1) * 8;
    } else {
        tilepx = w * APX;
    }
    const int co_base = blockIdx.y * 64;

    const int ly = ((n >> 3) & 1) * 2 + ((n >> 1) & 1);
    const int lx = ((n >> 2) & 1) * 2 + (n & 1);

    int abase[4], wbase[4];
#pragma unroll
    for (int ps = 0; ps < 4; ++ps) {
        int ay0 = wy8 + (ps >> 1) * 4 + ly;
        int ax0 = wx8 + (ps & 1) * 4 + lx;
        abase[ps] = q * APLANE + (tilepx + ay0 * ATX + ax0) * 16;
    }
#pragma unroll
    for (int cs = 0; cs < 4; ++cs)
        wbase[cs] = WBASE + q * WPLANE + ((cs * 16 + n) * 9) * 16;

    v4i acc[4][4];
#pragma unroll
    for (int ps = 0; ps < 4; ++ps)
#pragma unroll
        for (int cs = 0; cs < 4; ++cs)
            acc[ps][cs] = (v4i)0;

    for (int pass = 0; pass < NPASS; ++pass) {
        const int cib = pass * 64;
        __syncthreads();
        // --- activation staging: raw u8 NHWC 16B chunks -> plane-split LDS ---
        for (int i = tid; i < IPB * APX * 4; i += 256) {
            const int px_g = i >> 2, c = i & 3;
            int tile = 0, px = px_g;
            if (IPB == 4) { tile = px_g / APX; px = px_g - tile * APX; }
            const int gy = regY0 - 1 + px / ATX;
            const int gx = regX0 - 1 + px % ATX;
            const int bimg = (IPB == 1) ? img : ((int)blockIdx.x * 4 + tile);
            uint4 v = {0u, 0u, 0u, 0u};
            if ((unsigned)gy < (unsigned)H && (unsigned)gx < (unsigned)W)
                v = *(const uint4*)&in[((bimg * H + gy) * W + gx) * CI + cib + c * 16];
            *(uint4*)&lds[c * APLANE + px_g * 16] = v;
        }
        // --- weight staging: raw i8 [co][tap][ci-chunk] -> plane-split LDS ---
        for (int i = tid; i < 2304; i += 256) {
            const int row = i >> 2, c = i & 3;
            const int co_l = row / 9, tap = row - co_l * 9;
            uint4 v = *(const uint4*)&wt[((co_base + co_l) * 9 + tap) * CI + cib + c * 16];
            *(uint4*)&lds[WBASE + c * WPLANE + row * 16] = v;
        }
        __syncthreads();

#pragma unroll
        for (int tap = 0; tap < 9; ++tap) {
            const int toff = ((tap / 3) * ATX + (tap % 3)) * 16;
            v4i bf[4], af[4];
#pragma unroll
            for (int cs = 0; cs < 4; ++cs)
                bf[cs] = *(const v4i*)&lds[wbase[cs] + tap * 16];
#pragma unroll
            for (int ps = 0; ps < 4; ++ps)
                af[ps] = *(const v4i*)&lds[abase[ps] + toff];
#pragma unroll
            for (int ps = 0; ps < 4; ++ps)
#pragma unroll
                for (int cs = 0; cs < 4; ++cs)
                    acc[ps][cs] = __builtin_amdgcn_mfma_i32_16x16x64_i8(
                        af[ps], bf[cs], acc[ps][cs], 0, 0, 0);
        }
    }

    // --- epilogue: division-free fp64 affine+quant+relu, intra-lane 2x2 pool ---
    // 7y = acc*(g/7) + 7b  (conv = acc/49; 7*(1/49) = 1/7); q = clamp(rint,0,7)
    const int bimg = (IPB == 1) ? img : ((int)blockIdx.x * 4 + w);
#pragma unroll
    for (int cs = 0; cs < 4; ++cs) {
        const int co = co_base + cs * 16 + n;
        const double g7 = (double)gvec[co] * (1.0 / 7.0);
        const double b7 = (double)bvec[co] * 7.0;
#pragma unroll
        for (int ps = 0; ps < 4; ++ps) {
            const int Yb = regY0 + wy8 + (ps >> 1) * 4 + (q >> 1) * 2;
            const int Xb = regX0 + wx8 + (ps & 1) * 4 + (q & 1) * 2;
            int r4[4];
#pragma unroll
            for (int r = 0; r < 4; ++r) {
                int qi = (int)rint(fma((double)acc[ps][cs][r], g7, b7));
                r4[r] = qi < 0 ? 0 : (qi > 7 ? 7 : qi);
            }
            if (POOL) {
                int m = max(max(r4[0], r4[1]), max(r4[2], r4[3]));
                out[((bimg * (H / 2) + (Yb >> 1)) * (W / 2) + (Xb >> 1)) * CO + co] = (unsigned char)m;
            } else {
#pragma unroll
                for (int r = 0; r < 4; ++r) {
                    const int Y = Yb + (r >> 1), X = Xb + (r & 1);
                    out[((bimg * H + Y) * W + X) * CO + co] = (unsigned char)r4[r];
                }
            }
        }
    }
}

// ---------------------------------------------------------------------------
// FC1: h[512][4096] u8 x wt[512][4096] i8 -> u8 [512][512], i8 MFMA,
// 32x32 output tile, 4 waves split K=4096 into 1024 each, LDS reduce.
// ---------------------------------------------------------------------------
__global__ __launch_bounds__(256, 2) void fc1_i8_k(
    const unsigned char* __restrict__ h, const signed char* __restrict__ wt,
    const float* __restrict__ gvec, const float* __restrict__ bvec,
    unsigned char* __restrict__ out)
{
    __shared__ int red[4096];
    const int tid = threadIdx.x;
    const int l = tid & 63, w = tid >> 6;
    const int n = l & 15, q = l >> 4;
    const int m0 = blockIdx.x * 32, n0 = blockIdx.y * 32;

    v4i acc[2][2];
#pragma unroll
    for (int a = 0; a < 2; ++a)
#pragma unroll
        for (int b = 0; b < 2; ++b) acc[a][b] = (v4i)0;

    const int kb = w * 1024;
    for (int ks = 0; ks < 16; ++ks) {
        const int k = kb + ks * 64 + q * 16;
        v4i af[2], bf[2];
#pragma unroll
        for (int ms = 0; ms < 2; ++ms)
            af[ms] = *(const v4i*)&h[(m0 + ms * 16 + n) * 4096 + k];
#pragma unroll
        for (int ns = 0; ns < 2; ++ns)
            bf[ns] = *(const v4i*)&wt[(n0 + ns * 16 + n) * 4096 + k];
#pragma unroll
        for (int ms = 0; ms < 2; ++ms)
#pragma unroll
            for (int ns = 0; ns < 2; ++ns)
                acc[ms][ns] = __builtin_amdgcn_mfma_i32_16x16x64_i8(
                    af[ms], bf[ns], acc[ms][ns], 0, 0, 0);
    }

#pragma unroll
    for (int ms = 0; ms < 2; ++ms)
#pragma unroll
        for (int ns = 0; ns < 2; ++ns)
#pragma unroll
            for (int r = 0; r < 4; ++r)
                red[w * 1024 + (ms * 16 + q * 4 + r) * 32 + ns * 16 + n] = acc[ms][ns][r];
    __syncthreads();

#pragma unroll
    for (int j = 0; j < 4; ++j) {
        const int e = tid * 4 + j;
        int s = red[e] + red[1024 + e] + red[2048 + e] + red[3072 + e];
        const int ml = e >> 5, nl = e & 31;
        const int co = n0 + nl;
        double y7 = fma((double)s, (double)gvec[co] * (1.0 / 7.0), (double)bvec[co] * 7.0);
        int qi = (int)rint(y7);
        qi = qi < 0 ? 0 : (qi > 7 ? 7 : qi);
        out[(m0 + ml) * 512 + co] = (unsigned char)qi;
    }
}

// FC2: tiny (proven exact; left untouched)
__global__ __launch_bounds__(256) void fc2_k(
    const unsigned char* __restrict__ h, const signed char* __restrict__ wq,
    const float* __restrict__ gvec, const float* __restrict__ bvec,
    float* __restrict__ out)
{
    const int gid = blockIdx.x * 256 + threadIdx.x;
    const int b = gid >> 4;
    const int n = gid & 15;
    if (b >= 512 || n >= 10) return;
    int s = 0;
    for (int k = 0; k < 512; ++k)
        s += (int)h[b * 512 + k] * (int)wq[n * 512 + k];
    double y = ((double)s / 49.0) * (double)gvec[n] + (double)bvec[n];
    double t = fmin(fmax(y, -1.0), 1.0) * 7.0;
    double r = rint(t);
    out[b * 10 + n] = (float)(r / 7.0);
}

// ---------------------------------------------------------------------------
extern "C" void kernel_launch(void* const* d_in, const int* in_sizes, int n_in,
                              void* d_out, int out_size, void* d_ws, size_t ws_size,
                              hipStream_t stream) {
    const float* x   = (const float*)d_in[0];
    const float* w1  = (const float*)d_in[1];
    const float* g1  = (const float*)d_in[2];
    const float* b1  = (const float*)d_in[3];
    const float* w2  = (const float*)d_in[4];
    const float* g2  = (const float*)d_in[5];
    const float* b2  = (const float*)d_in[6];
    const float* w3  = (const float*)d_in[7];
    const float* g3  = (const float*)d_in[8];
    const float* b3  = (const float*)d_in[9];
    const float* w4  = (const float*)d_in[10];
    const float* g4  = (const float*)d_in[11];
    const float* b4  = (const float*)d_in[12];
    const float* w5  = (const float*)d_in[13];
    const float* g5  = (const float*)d_in[14];
    const float* b5  = (const float*)d_in[15];
    const float* w6  = (const float*)d_in[16];
    const float* g6  = (const float*)d_in[17];
    const float* b6  = (const float*)d_in[18];
    const float* wf1 = (const float*)d_in[19];
    const float* gf1 = (const float*)d_in[20];
    const float* bf1 = (const float*)d_in[21];
    const float* wf2 = (const float*)d_in[22];
    const float* gf2 = (const float*)d_in[23];
    const float* bf2 = (const float*)d_in[24];

    char* ws = (char*)d_ws;
    signed char*   qw1  = (signed char*)(ws + O_QW1);
    signed char*   qwf2 = (signed char*)(ws + O_QWF2);
    signed char*   qwt2 = (signed char*)(ws + O_QWT2);
    signed char*   qwt3 = (signed char*)(ws + O_QWT3);
    signed char*   qwt4 = (signed char*)(ws + O_QWT4);
    signed char*   qwt5 = (signed char*)(ws + O_QWT5);
    signed char*   qwt6 = (signed char*)(ws + O_QWT6);
    signed char*   qwf1 = (signed char*)(ws + O_QWF1);
    unsigned char* bufA = (unsigned char*)(ws + O_BUFA);
    unsigned char* bufB = (unsigned char*)(ws + O_BUFB);

    // weight prep: single fused launch
    hipLaunchKernelGGL(prep_k, dim3(12683), dim3(256), 0, stream,
                       w1, qw1, wf2, qwf2, w2, qwt2, w3, qwt3,
                       w4, qwt4, w5, qwt5, w6, qwt6, wf1, qwf1);

    // conv stack
    hipLaunchKernelGGL(conv1_k, dim3(2048, 4), dim3(256), 0, stream, x, qw1, g1, b1, bufA);
    hipLaunchKernelGGL((conv_i8_k<64,  64,  32, 32, true,  1>), dim3(2048, 1), dim3(256), 0, stream, bufA, qwt2, g2, b2, bufB);
    hipLaunchKernelGGL((conv_i8_k<64,  128, 16, 16, false, 1>), dim3(512,  2), dim3(256), 0, stream, bufB, qwt3, g3, b3, bufA);
    hipLaunchKernelGGL((conv_i8_k<128, 128, 16, 16, true,  1>), dim3(512,  2), dim3(256), 0, stream, bufA, qwt4, g4, b4, bufB);
    hipLaunchKernelGGL((conv_i8_k<128, 256, 8,  8,  false, 4>), dim3(128,  4), dim3(256), 0, stream, bufB, qwt5, g5, b5, bufA);
    hipLaunchKernelGGL((conv_i8_k<256, 256, 8,  8,  true,  4>), dim3(128,  4), dim3(256), 0, stream, bufA, qwt6, g6, b6, bufB);

    // FC head
    hipLaunchKernelGGL(fc1_i8_k, dim3(16, 16), dim3(256), 0, stream, bufB, qwf1, gf1, bf1, bufA);
    hipLaunchKernelGGL(fc2_k, dim3(32), dim3(256), 0, stream, bufA, qwf2, gf2, bf2, (float*)d_out);
}